// Round 20
// baseline (57.118 us; speedup 1.0000x reference)
//
#include <hip/hip_runtime.h>
#include <hip/hip_bf16.h>
#include <math.h>

#define NROWS 16384
#define DIN   784
#define DZ    100
#define NS    10
#define KTILES 25          // 16x16 frag tiling for pv (25*32 = 800, tail zeroed)
#define KT32  49           // 32x32 K-tiles for colmean (49*16 = 784 exactly)
#define NCT32 7            // 7 col-tiles of 32 = 224 cols (200 real + 24 zero)
#define BND_THR 45.0f
#define KTP2  520          // frag-set stride in ushorts (1040B): bank-spread

typedef unsigned short ushort_t;
typedef short bf16x8 __attribute__((ext_vector_type(8)));
typedef float f32x4  __attribute__((ext_vector_type(4)));
typedef float f32x16 __attribute__((ext_vector_type(16)));

// ws: [0..199] colsums (atomic)  [200] pv sum  [203] done-counter
//     [208..8047] y2[s][i] = y*log2e
// byte 64KB..: Wb2 bf16 32x32-frag W (49*7*512 ushorts = 343 KB)
#define WS_Y2 208
#define WB_OFF_BYTES (64u * 1024u)

__device__ __forceinline__ float softplus_fast(float v) {
    // ln(1+e^v) = (max(t,0) + log2(1+2^-|t|)) * ln2, t = v*log2e
    float t = v * 1.44269504088896f;
    return (fmaxf(t, 0.f)
            + __builtin_amdgcn_logf(1.f + __builtin_amdgcn_exp2f(-fabsf(t))))
           * 0.69314718055995f;
}
__device__ __forceinline__ unsigned pack2(float lo, float hi) {
    float2 f2; f2.x = lo; f2.y = hi;
    __hip_bfloat162 h2 = __float22bfloat162_rn(f2);
    return *reinterpret_cast<unsigned*>(&h2);
}

// ---- W -> bf16 32x32x16 B-frags + ws zero ----
// Wb2[((kt*7 + ct)*64 + l)*8 + j] = W[ct*32 + (l&31)][kt*16 + (l>>5)*8 + j]
__global__ __launch_bounds__(256) void wb2_kernel(
    const float* __restrict__ W0, const float* __restrict__ W1,
    ushort_t* __restrict__ Wb, float* __restrict__ ws)
{
    if (blockIdx.x == 0) ws[threadIdx.x] = 0.f;    // sums + counters
    int t = blockIdx.x * 256 + threadIdx.x;
    if (t >= KT32 * NCT32 * 64) return;
    int kt  = t / (NCT32 * 64);
    int rem = t - kt * (NCT32 * 64);
    int ct = rem >> 6, l = rem & 63;
    int col = ct * 32 + (l & 31);
    int k0  = kt * 16 + (l >> 5) * 8;              // always < 784
    uint4 o = make_uint4(0u, 0u, 0u, 0u);
    if (col < 200) {
        const float* src = (col < 100 ? W0 + (size_t)col * DIN
                                      : W1 + (size_t)(col - 100) * DIN) + k0;
        float4 a = *(const float4*)src;
        float4 b = *(const float4*)(src + 4);
        o.x = pack2(a.x, a.y); o.y = pack2(a.z, a.w);
        o.z = pack2(b.x, b.y); o.w = pack2(b.z, b.w);
    }
    *(uint4*)(Wb + (size_t)t * 8) = o;
}

// ---- colmean m: 32x32x16 MFMA, B-stationary waves ----
// 256 blocks x 896 thr (14 waves = 2 rowtiles x 7 col-tiles). Block = 64 rows.
// Stage: coalesced x reads -> 32x32 A-frags in LDS (102 KB), ONE barrier.
// K-loop (49 kt): per wave 1 ds_read_b128 A + 1 coalesced B-load + 1 MFMA;
// zero barriers, named reg dbuf. 2.3x fewer LDS ops than the 16x16 version.
__global__ __launch_bounds__(896) void colmean_m(
    const float* __restrict__ x, const ushort_t* __restrict__ Wb,
    const float* __restrict__ b0, const float* __restrict__ b1,
    float* __restrict__ ws)
{
    __shared__ ushort_t xls[2 * KT32 * KTP2];      // 101.9 KB
    const int tid = threadIdx.x;
    const int lane = tid & 63, w = tid >> 6;
    const int row0 = blockIdx.x * 64;

    // ---- stage: 6272 slots = 64 rows x 98 (kt,kg) chunks of 8 elems ----
#pragma unroll
    for (int i = 0; i < 7; ++i) {
        int slot = tid + i * 896;                  // consecutive tid -> consecutive k
        int r  = slot / 98;
        int sc = slot - r * 98;                    // sc = kt*2 + kg
        int kt = sc >> 1, kg = sc & 1;
        const float* src = x + (size_t)(row0 + r) * DIN + sc * 8;
        float4 a = *(const float4*)src, b = *(const float4*)(src + 4);
        uint4 o;
        o.x = pack2(a.x, a.y); o.y = pack2(a.z, a.w);
        o.z = pack2(b.x, b.y); o.w = pack2(b.z, b.w);
        int l = kg * 32 + (r & 31);
        *(uint4*)&xls[((size_t)(r >> 5) * KT32 + kt) * KTP2 + l * 8] = o;
    }
    __syncthreads();

    // ---- K-loop ----
    const int rt = w & 1, ct = w >> 1;
    const ushort_t* ap  = xls + (size_t)rt * KT32 * KTP2 + lane * 8;
    const ushort_t* wbp = Wb + (size_t)ct * 512 + lane * 8;   // + kt*3584

    f32x16 acc;
#pragma unroll
    for (int r = 0; r < 16; ++r) acc[r] = 0.f;

    bf16x8 Aa, Ab;
    uint4  Ba, Bb;
    auto ld = [&](int kt, bf16x8& A, uint4& B) {
        A = *(const bf16x8*)(ap + (size_t)kt * KTP2);
        B = *(const uint4*)(wbp + (size_t)kt * (NCT32 * 512));
    };
    auto cp = [&](const bf16x8& A, const uint4& B) {
        acc = __builtin_amdgcn_mfma_f32_32x32x16_bf16(A, *(const bf16x8*)&B, acc, 0, 0, 0);
    };

    ld(0, Aa, Ba);
    for (int i = 0; i < 24; ++i) {
        ld(2 * i + 1, Ab, Bb);
        cp(Aa, Ba);
        ld(2 * i + 2, Aa, Ba);
        cp(Ab, Bb);
    }
    cp(Aa, Ba);                                    // kt = 48

    // ---- epilogue: C col = lane&31 (HW-measured); rows permute-invariant ----
    const int j = ct * 32 + (lane & 31);
    const float bias = (j < 100) ? b0[j] : ((j < 200) ? b1[j - 100] : 0.f);
    float v = 0.f;
#pragma unroll
    for (int r = 0; r < 16; ++r) v += softplus_fast(acc[r] + bias);
    v += __shfl_xor(v, 32);                        // combine the two 16-row halves
    if (lane < 32 && j < 200) atomicAdd(&ws[j], v);
}

// ---- y2 = (z @ W2.T + b2) * log2e with z computed inline from colsums ----
__global__ __launch_bounds__(256) void y2z_kernel(
    const float* __restrict__ W2, const float* __restrict__ b2,
    const float* __restrict__ eps, float* __restrict__ ws)
{
    int wid  = (int)((blockIdx.x * 256 + threadIdx.x) >> 6);
    int lane = threadIdx.x & 63;
    if (wid >= NS * DIN) return;
    int s = wid / DIN, i = wid % DIN;
    const float inv = 1.f / (float)NROWS;
    const float* wr = W2 + (size_t)i * DZ;
    const float* er = eps + (size_t)s * DZ;
    float p = 0.f;
    for (int d = lane; d < DZ; d += 64) {
        float zd = inv * (ws[d] + ws[100 + d] * er[d]);
        p += zd * wr[d];
    }
#pragma unroll
    for (int off = 32; off > 0; off >>= 1) p += __shfl_xor(p, off);
    if (lane == 0) ws[WS_Y2 + wid] = (p + b2[i]) * 1.4426950408889634f;
}

// ---- pv + fused finalization (R16-proven, direct x, 16x16 frags) ----
// MFMA-certified bound: sum_i max(u,0) = 0.5*(n.y + |n|.|y|), u=(1-2x)*y2 (log2).
// bnd >= 45 => p < 2^-43 << ulp(0.001)/2 => term == ln(0.001) exactly.
__global__ __launch_bounds__(256, 4) void pv_final_kernel(
    const float* __restrict__ x, float* __restrict__ ws,
    const float* __restrict__ eps, float* __restrict__ out, int nblocks)
{
    __shared__ ushort_t yf[KTILES * 512];   // y2 B-frags (bf16)
    __shared__ ushort_t ya[KTILES * 512];   // |y2| B-frags
    __shared__ float bsum;
    __shared__ int lastflag;
    __shared__ float dred[256];
    const int tid = threadIdx.x;
    const int lane = tid & 63, w = tid >> 6;

    for (int idx = tid; idx < KTILES * 64; idx += 256) {
        int kt = idx >> 6, l = idx & 63;
        int ss = l & 15, k0 = kt * 32 + (l >> 4) * 8;
        uint4 o = make_uint4(0u, 0u, 0u, 0u), oa = o;
        if (ss < NS && k0 < DIN) {
            const float* src = ws + WS_Y2 + ss * DIN + k0;
            float4 a = *(const float4*)src, b = *(const float4*)(src + 4);
            o.x = pack2(a.x, a.y); o.y = pack2(a.z, a.w);
            o.z = pack2(b.x, b.y); o.w = pack2(b.z, b.w);
            oa.x = o.x & 0x7FFF7FFFu; oa.y = o.y & 0x7FFF7FFFu;
            oa.z = o.z & 0x7FFF7FFFu; oa.w = o.w & 0x7FFF7FFFu;
        }
        *(uint4*)(yf + (size_t)idx * 8) = o;
        *(uint4*)(ya + (size_t)idx * 8) = oa;
    }
    if (tid == 0) { bsum = 0.f; lastflag = 0; }
    __syncthreads();

    const int tile = blockIdx.x * 4 + w;       // 1024 tiles of 16 rows
    const int row  = tile * 16 + (lane & 15);
    const int kc   = lane >> 4;
    const int s    = lane & 15;
    const float* xp = x + (size_t)row * DIN;
    const float L001 = -6.90775527898f;        // ln(0.001f)

    f32x4 acc0 = (f32x4){0.f, 0.f, 0.f, 0.f};
    f32x4 acc1 = (f32x4){0.f, 0.f, 0.f, 0.f};
    float4 a0A, a1A, a0B, a1B;

    auto loadA = [&](int kt, float4& a0, float4& a1) {
        int k0 = kt * 32 + kc * 8;
        if (k0 + 8 > DIN) k0 = 768;            // junk ok: y frags zero there
        a0 = *(const float4*)(xp + k0);
        a1 = *(const float4*)(xp + k0 + 4);
    };
    auto comp = [&](int kt, const float4& a0, const float4& a1) {
        bf16x8 nf; unsigned* p = (unsigned*)&nf;
        p[0] = pack2(1.f - 2.f * a0.x, 1.f - 2.f * a0.y);
        p[1] = pack2(1.f - 2.f * a0.z, 1.f - 2.f * a0.w);
        p[2] = pack2(1.f - 2.f * a1.x, 1.f - 2.f * a1.y);
        p[3] = pack2(1.f - 2.f * a1.z, 1.f - 2.f * a1.w);
        bf16x8 na; unsigned* q = (unsigned*)&na;
        q[0] = p[0] & 0x7FFF7FFFu; q[1] = p[1] & 0x7FFF7FFFu;
        q[2] = p[2] & 0x7FFF7FFFu; q[3] = p[3] & 0x7FFF7FFFu;
        bf16x8 fy = *(const bf16x8*)(yf + (size_t)kt * 512 + lane * 8);
        bf16x8 fa = *(const bf16x8*)(ya + (size_t)kt * 512 + lane * 8);
        acc0 = __builtin_amdgcn_mfma_f32_16x16x32_bf16(nf, fy, acc0, 0, 0, 0);
        acc1 = __builtin_amdgcn_mfma_f32_16x16x32_bf16(na, fa, acc1, 0, 0, 0);
    };
    loadA(0, a0A, a1A);
    for (int i = 0; i < 12; ++i) {
        loadA(2 * i + 1, a0B, a1B);
        comp(2 * i, a0A, a1A);
        loadA(2 * i + 2, a0A, a1A);
        comp(2 * i + 1, a0B, a1B);
    }
    comp(24, a0A, a1A);

    float bnd[4];
#pragma unroll
    for (int r = 0; r < 4; ++r) bnd[r] = 0.5f * (acc0[r] + acc1[r]);
    float wsum;
    bool lslow = (s < NS) &&
        (fminf(fminf(bnd[0], bnd[1]), fminf(bnd[2], bnd[3])) < BND_THR);
    unsigned long long m = __ballot(lslow);
    if (m == 0ull) {
        wsum = 160.f * L001;                   // 16 rows x 10 samples, all certified
    } else {
        int nslow = 0;
        float slowsum = 0.f;
#pragma unroll
        for (int r = 0; r < 4; ++r) {
            unsigned long long mr = __ballot((s < NS) && (bnd[r] < BND_THR));
            nslow += (int)__popcll(mr);
            while (mr) {
                int src = (int)__ffsll(mr) - 1; mr &= (mr - 1);
                int ss = src & 15;
                int rrow = tile * 16 + (src >> 4) * 4 + r;
                const float* xq = x + (size_t)rrow * DIN;
                const float* yq = ws + WS_Y2 + ss * DIN;
                float a = 0.f;
                for (int i = lane; i < DIN; i += 64)
                    a -= __builtin_amdgcn_logf(
                        1.f + __builtin_amdgcn_exp2f((1.f - 2.f * xq[i]) * yq[i]));
#pragma unroll
                for (int off = 32; off > 0; off >>= 1) a += __shfl_xor(a, off);
                slowsum += __logf(__builtin_amdgcn_exp2f(a) + 0.001f);
            }
        }
        wsum = (float)(160 - nslow) * L001 + slowsum;
    }
    if (lane == 0) atomicAdd(&bsum, wsum);
    __syncthreads();

    if (tid == 0) {
        atomicAdd(&ws[200], bsum);
        __threadfence();
        unsigned old = atomicAdd((unsigned*)&ws[203], 1u);
        if (old == (unsigned)(nblocks - 1)) lastflag = 1;
    }
    __syncthreads();
    if (lastflag) {
        __threadfence();
        float contrib = 0.f;
        if (tid < DZ) {
            const float inv = 1.f / (float)NROWS;
            float mm = ws[tid] * inv;
            float cc = ws[100 + tid] * inv;
            contrib = 0.5f * __logf(cc);
#pragma unroll
            for (int ss2 = 0; ss2 < NS; ++ss2) {
                float e = eps[ss2 * DZ + tid];
                float zz = mm + cc * e;
                contrib += (0.5f * cc * e * e - 0.5f * zz * zz) * (1.f / NS);
            }
        }
        dred[tid] = contrib;
        __syncthreads();
        for (int off = 128; off > 0; off >>= 1) {
            if (tid < off) dred[tid] += dred[tid + off];
            __syncthreads();
        }
        if (tid == 0) {
            float S = atomicAdd(&ws[200], 0.f);
            float E = S * (1.f / ((float)NROWS * (float)NS));
            out[0] = -(E + dred[0]);
        }
    }
}

extern "C" void kernel_launch(void* const* d_in, const int* in_sizes, int n_in,
                              void* d_out, int out_size, void* d_ws, size_t ws_size,
                              hipStream_t stream)
{
    const float* x   = (const float*)d_in[0];
    const float* W0  = (const float*)d_in[1];
    const float* b0  = (const float*)d_in[2];
    const float* W1  = (const float*)d_in[3];
    const float* b1  = (const float*)d_in[4];
    const float* W2  = (const float*)d_in[5];
    const float* b2  = (const float*)d_in[6];
    const float* eps = (const float*)d_in[7];
    float* out = (float*)d_out;
    float* ws  = (float*)d_ws;
    ushort_t* Wb = (ushort_t*)((char*)d_ws + WB_OFF_BYTES);

    wb2_kernel<<<(KT32 * NCT32 * 64 + 255) / 256, 256, 0, stream>>>(W0, W1, Wb, ws);
    colmean_m<<<NROWS / 64, 896, 0, stream>>>(x, Wb, b0, b1, ws);
    y2z_kernel<<<(NS * DIN * 64) / 256, 256, 0, stream>>>(W2, b2, eps, ws);
    pv_final_kernel<<<256, 256, 0, stream>>>(x, ws, eps, out, 256);
}

// Round 21
// 50.976 us; speedup vs baseline: 1.1205x; 1.1205x over previous
//
#include <hip/hip_runtime.h>
#include <hip/hip_bf16.h>
#include <math.h>

#define NROWS 16384
#define DIN   784
#define DZ    100
#define NS    10
#define NCT   16           // 16 col-tiles x 16 = 256 cols (200 real + 56 zero pad)
#define KTILES 25          // 25 * 32 = 800 >= 784, tail frags zeroed
#define BND_THR 45.0f
#define KTPAD 520          // kt-stride in ushorts (1040B)

typedef unsigned short ushort_t;
typedef short bf16x8 __attribute__((ext_vector_type(8)));
typedef float f32x4  __attribute__((ext_vector_type(4)));

// ws: [0..199] colsums (atomic)  [200] pv sum  [203] done-counter
//     [208..8047] y2[s][i] = y*log2e
// byte 64KB..: Wb bf16 frag-swizzled W (400 KB)
#define WS_Y2 208
#define WB_OFF_BYTES (64u * 1024u)

__device__ __forceinline__ float softplus_fast(float v) {
    // ln(1+e^v) = (max(t,0) + log2(1+2^-|t|)) * ln2, t = v*log2e
    float t = v * 1.44269504088896f;
    return (fmaxf(t, 0.f)
            + __builtin_amdgcn_logf(1.f + __builtin_amdgcn_exp2f(-fabsf(t))))
           * 0.69314718055995f;
}
__device__ __forceinline__ unsigned pack2(float lo, float hi) {
    float2 f2; f2.x = lo; f2.y = hi;
    __hip_bfloat162 h2 = __float22bfloat162_rn(f2);
    return *reinterpret_cast<unsigned*>(&h2);
}

// ---- W -> bf16 B-frags + ws zero ----
// Wb[((kt*16 + ct)*64 + l)*8 + j] = W[ct*16 + (l&15)][kt*32 + (l>>4)*8 + j]
__global__ __launch_bounds__(256) void wb_kernel(
    const float* __restrict__ W0, const float* __restrict__ W1,
    ushort_t* __restrict__ Wb, float* __restrict__ ws)
{
    if (blockIdx.x == 0) ws[threadIdx.x] = 0.f;    // sums + counters
    int t = blockIdx.x * 256 + threadIdx.x;
    if (t >= KTILES * NCT * 64) return;
    int kt = t >> 10;
    int r  = t & 1023;
    int ct = r >> 6, l = r & 63;
    int col = ct * 16 + (l & 15);
    int k0  = kt * 32 + (l >> 4) * 8;
    uint4 o = make_uint4(0u, 0u, 0u, 0u);
    if (col < 200 && k0 < DIN) {
        const float* src = (col < 100 ? W0 + (size_t)col * DIN
                                      : W1 + (size_t)(col - 100) * DIN) + k0;
        float4 a = *(const float4*)src;
        float4 b = *(const float4*)(src + 4);
        o.x = pack2(a.x, a.y); o.y = pack2(a.z, a.w);
        o.z = pack2(b.x, b.y); o.w = pack2(b.z, b.w);
    }
    *(uint4*)(Wb + (size_t)t * 8) = o;
}

// ---- colmean h (R16-proven): B-STATIONARY waves. 256 blocks x 1024 thr ----
// Block = 64 rows; wave w owns col-tile w for ALL 4 rowtiles. Per kt:
// 1 B-load (global, dbuf) + 4 ds_read_b128 A-frags + 4 MFMA (4 indep chains).
// Stage: coalesced x reads -> bf16 A-frags in LDS (104 KB), ONE barrier.
__global__ __launch_bounds__(1024) void colmean_h(
    const float* __restrict__ x, const ushort_t* __restrict__ Wb,
    const float* __restrict__ b0, const float* __restrict__ b1,
    float* __restrict__ ws)
{
    __shared__ ushort_t xls[4 * KTILES * KTPAD];   // 104 KB
    const int tid = threadIdx.x;
    const int lane = tid & 63, w = tid >> 6;
    const int row0 = blockIdx.x * 64;

    // ---- stage ----
    for (int slot = tid; slot < 6400; slot += 1024) {  // slot = r*100 + kt*4 + kc
        int r  = slot / 100;
        int sl = slot - r * 100;
        int kt = sl >> 2, kc = sl & 3;
        int k0 = kt * 32 + kc * 8;
        uint4 o = make_uint4(0u, 0u, 0u, 0u);
        if (k0 + 8 <= DIN) {
            const float* src = x + (size_t)(row0 + r) * DIN + k0;
            float4 a = *(const float4*)src, b = *(const float4*)(src + 4);
            o.x = pack2(a.x, a.y); o.y = pack2(a.z, a.w);
            o.z = pack2(b.x, b.y); o.w = pack2(b.z, b.w);
        }
        int l = (kc << 4) | (r & 15);
        *(uint4*)&xls[((size_t)(r >> 4) * KTILES + kt) * KTPAD + l * 8] = o;
    }
    __syncthreads();

    // ---- K-loop: zero barriers, named reg dbuf, B stationary per wave ----
    const ushort_t* ap  = xls + lane * 8;                  // + rt*KTILES*KTPAD + kt*KTPAD
    const ushort_t* wbp = Wb + (size_t)w * 512 + lane * 8; // + kt*8192

    f32x4 acc0 = (f32x4){0.f,0.f,0.f,0.f}, acc1 = acc0, acc2 = acc0, acc3 = acc0;

    bf16x8 Aa[4], Ab[4];
    uint4  Ba, Bb;

    auto ld = [&](int kt, bf16x8 (&A)[4], uint4& B) {
#pragma unroll
        for (int rt = 0; rt < 4; ++rt)
            A[rt] = *(const bf16x8*)(ap + (size_t)rt * KTILES * KTPAD + (size_t)kt * KTPAD);
        B = *(const uint4*)(wbp + (size_t)kt * 8192);
    };
    auto cp = [&](const bf16x8 (&A)[4], const uint4& B) {
        bf16x8 bf = *(const bf16x8*)&B;
        acc0 = __builtin_amdgcn_mfma_f32_16x16x32_bf16(A[0], bf, acc0, 0, 0, 0);
        acc1 = __builtin_amdgcn_mfma_f32_16x16x32_bf16(A[1], bf, acc1, 0, 0, 0);
        acc2 = __builtin_amdgcn_mfma_f32_16x16x32_bf16(A[2], bf, acc2, 0, 0, 0);
        acc3 = __builtin_amdgcn_mfma_f32_16x16x32_bf16(A[3], bf, acc3, 0, 0, 0);
    };

    ld(0, Aa, Ba);
    for (int i = 0; i < 12; ++i) {
        ld(2 * i + 1, Ab, Bb);
        cp(Aa, Ba);
        ld(2 * i + 2, Aa, Ba);
        cp(Ab, Bb);
    }
    cp(Aa, Ba);                            // kt = 24

    // ---- epilogue: wave owns complete 64-row sums for its 16 cols ----
    const int j = w * 16 + (lane & 15);
    const float bias = (j < 100) ? b0[j] : ((j < 200) ? b1[j - 100] : 0.f);
    float v = 0.f;
#pragma unroll
    for (int r = 0; r < 4; ++r)
        v += softplus_fast(acc0[r] + bias) + softplus_fast(acc1[r] + bias)
           + softplus_fast(acc2[r] + bias) + softplus_fast(acc3[r] + bias);
    v += __shfl_xor(v, 16);
    v += __shfl_xor(v, 32);
    if ((lane >> 4) == 0 && j < 200) atomicAdd(&ws[j], v);
}

// ---- y2 = (z @ W2.T + b2) * log2e with z computed inline from colsums ----
__global__ __launch_bounds__(256) void y2z_kernel(
    const float* __restrict__ W2, const float* __restrict__ b2,
    const float* __restrict__ eps, float* __restrict__ ws)
{
    int wid  = (int)((blockIdx.x * 256 + threadIdx.x) >> 6);
    int lane = threadIdx.x & 63;
    if (wid >= NS * DIN) return;
    int s = wid / DIN, i = wid % DIN;
    const float inv = 1.f / (float)NROWS;
    const float* wr = W2 + (size_t)i * DZ;
    const float* er = eps + (size_t)s * DZ;
    float p = 0.f;
    for (int d = lane; d < DZ; d += 64) {
        float zd = inv * (ws[d] + ws[100 + d] * er[d]);
        p += zd * wr[d];
    }
#pragma unroll
    for (int off = 32; off > 0; off >>= 1) p += __shfl_xor(p, off);
    if (lane == 0) ws[WS_Y2 + wid] = (p + b2[i]) * 1.4426950408889634f;
}

// ---- pv + fused finalization (R16-proven, direct x) ----
// MFMA-certified bound: sum_i max(u,0) = 0.5*(n.y + |n|.|y|), u=(1-2x)*y2 (log2).
// bnd >= 45 => p < 2^-43 << ulp(0.001)/2 => term == ln(0.001) exactly.
__global__ __launch_bounds__(256, 4) void pv_final_kernel(
    const float* __restrict__ x, float* __restrict__ ws,
    const float* __restrict__ eps, float* __restrict__ out, int nblocks)
{
    __shared__ ushort_t yf[KTILES * 512];   // y2 B-frags (bf16)
    __shared__ ushort_t ya[KTILES * 512];   // |y2| B-frags
    __shared__ float bsum;
    __shared__ int lastflag;
    __shared__ float dred[256];
    const int tid = threadIdx.x;
    const int lane = tid & 63, w = tid >> 6;

    for (int idx = tid; idx < KTILES * 64; idx += 256) {
        int kt = idx >> 6, l = idx & 63;
        int ss = l & 15, k0 = kt * 32 + (l >> 4) * 8;
        uint4 o = make_uint4(0u, 0u, 0u, 0u), oa = o;
        if (ss < NS && k0 < DIN) {
            const float* src = ws + WS_Y2 + ss * DIN + k0;
            float4 a = *(const float4*)src, b = *(const float4*)(src + 4);
            o.x = pack2(a.x, a.y); o.y = pack2(a.z, a.w);
            o.z = pack2(b.x, b.y); o.w = pack2(b.z, b.w);
            oa.x = o.x & 0x7FFF7FFFu; oa.y = o.y & 0x7FFF7FFFu;
            oa.z = o.z & 0x7FFF7FFFu; oa.w = o.w & 0x7FFF7FFFu;
        }
        *(uint4*)(yf + (size_t)idx * 8) = o;
        *(uint4*)(ya + (size_t)idx * 8) = oa;
    }
    if (tid == 0) { bsum = 0.f; lastflag = 0; }
    __syncthreads();

    const int tile = blockIdx.x * 4 + w;       // 1024 tiles of 16 rows
    const int row  = tile * 16 + (lane & 15);
    const int kc   = lane >> 4;
    const int s    = lane & 15;
    const float* xp = x + (size_t)row * DIN;
    const float L001 = -6.90775527898f;        // ln(0.001f)

    f32x4 acc0 = (f32x4){0.f, 0.f, 0.f, 0.f};
    f32x4 acc1 = (f32x4){0.f, 0.f, 0.f, 0.f};
    float4 a0A, a1A, a0B, a1B;

    auto loadA = [&](int kt, float4& a0, float4& a1) {
        int k0 = kt * 32 + kc * 8;
        if (k0 + 8 > DIN) k0 = 768;            // junk ok: y frags zero there
        a0 = *(const float4*)(xp + k0);
        a1 = *(const float4*)(xp + k0 + 4);
    };
    auto comp = [&](int kt, const float4& a0, const float4& a1) {
        bf16x8 nf; unsigned* p = (unsigned*)&nf;
        p[0] = pack2(1.f - 2.f * a0.x, 1.f - 2.f * a0.y);
        p[1] = pack2(1.f - 2.f * a0.z, 1.f - 2.f * a0.w);
        p[2] = pack2(1.f - 2.f * a1.x, 1.f - 2.f * a1.y);
        p[3] = pack2(1.f - 2.f * a1.z, 1.f - 2.f * a1.w);
        bf16x8 na; unsigned* q = (unsigned*)&na;
        q[0] = p[0] & 0x7FFF7FFFu; q[1] = p[1] & 0x7FFF7FFFu;
        q[2] = p[2] & 0x7FFF7FFFu; q[3] = p[3] & 0x7FFF7FFFu;
        bf16x8 fy = *(const bf16x8*)(yf + (size_t)kt * 512 + lane * 8);
        bf16x8 fa = *(const bf16x8*)(ya + (size_t)kt * 512 + lane * 8);
        acc0 = __builtin_amdgcn_mfma_f32_16x16x32_bf16(nf, fy, acc0, 0, 0, 0);
        acc1 = __builtin_amdgcn_mfma_f32_16x16x32_bf16(na, fa, acc1, 0, 0, 0);
    };
    loadA(0, a0A, a1A);
    for (int i = 0; i < 12; ++i) {
        loadA(2 * i + 1, a0B, a1B);
        comp(2 * i, a0A, a1A);
        loadA(2 * i + 2, a0A, a1A);
        comp(2 * i + 1, a0B, a1B);
    }
    comp(24, a0A, a1A);

    float bnd[4];
#pragma unroll
    for (int r = 0; r < 4; ++r) bnd[r] = 0.5f * (acc0[r] + acc1[r]);
    float wsum;
    bool lslow = (s < NS) &&
        (fminf(fminf(bnd[0], bnd[1]), fminf(bnd[2], bnd[3])) < BND_THR);
    unsigned long long m = __ballot(lslow);
    if (m == 0ull) {
        wsum = 160.f * L001;                   // 16 rows x 10 samples, all certified
    } else {
        int nslow = 0;
        float slowsum = 0.f;
#pragma unroll
        for (int r = 0; r < 4; ++r) {
            unsigned long long mr = __ballot((s < NS) && (bnd[r] < BND_THR));
            nslow += (int)__popcll(mr);
            while (mr) {
                int src = (int)__ffsll(mr) - 1; mr &= (mr - 1);
                int ss = src & 15;
                int rrow = tile * 16 + (src >> 4) * 4 + r;
                const float* xq = x + (size_t)rrow * DIN;
                const float* yq = ws + WS_Y2 + ss * DIN;
                float a = 0.f;
                for (int i = lane; i < DIN; i += 64)
                    a -= __builtin_amdgcn_logf(
                        1.f + __builtin_amdgcn_exp2f((1.f - 2.f * xq[i]) * yq[i]));
#pragma unroll
                for (int off = 32; off > 0; off >>= 1) a += __shfl_xor(a, off);
                slowsum += __logf(__builtin_amdgcn_exp2f(a) + 0.001f);
            }
        }
        wsum = (float)(160 - nslow) * L001 + slowsum;
    }
    if (lane == 0) atomicAdd(&bsum, wsum);
    __syncthreads();

    if (tid == 0) {
        atomicAdd(&ws[200], bsum);
        __threadfence();
        unsigned old = atomicAdd((unsigned*)&ws[203], 1u);
        if (old == (unsigned)(nblocks - 1)) lastflag = 1;
    }
    __syncthreads();
    if (lastflag) {
        __threadfence();
        float contrib = 0.f;
        if (tid < DZ) {
            const float inv = 1.f / (float)NROWS;
            float mm = ws[tid] * inv;
            float cc = ws[100 + tid] * inv;
            contrib = 0.5f * __logf(cc);
#pragma unroll
            for (int ss2 = 0; ss2 < NS; ++ss2) {
                float e = eps[ss2 * DZ + tid];
                float zz = mm + cc * e;
                contrib += (0.5f * cc * e * e - 0.5f * zz * zz) * (1.f / NS);
            }
        }
        dred[tid] = contrib;
        __syncthreads();
        for (int off = 128; off > 0; off >>= 1) {
            if (tid < off) dred[tid] += dred[tid + off];
            __syncthreads();
        }
        if (tid == 0) {
            float S = atomicAdd(&ws[200], 0.f);
            float E = S * (1.f / ((float)NROWS * (float)NS));
            out[0] = -(E + dred[0]);
        }
    }
}

extern "C" void kernel_launch(void* const* d_in, const int* in_sizes, int n_in,
                              void* d_out, int out_size, void* d_ws, size_t ws_size,
                              hipStream_t stream)
{
    const float* x   = (const float*)d_in[0];
    const float* W0  = (const float*)d_in[1];
    const float* b0  = (const float*)d_in[2];
    const float* W1  = (const float*)d_in[3];
    const float* b1  = (const float*)d_in[4];
    const float* W2  = (const float*)d_in[5];
    const float* b2  = (const float*)d_in[6];
    const float* eps = (const float*)d_in[7];
    float* out = (float*)d_out;
    float* ws  = (float*)d_ws;
    ushort_t* Wb = (ushort_t*)((char*)d_ws + WB_OFF_BYTES);

    wb_kernel<<<(KTILES * NCT * 64 + 255) / 256, 256, 0, stream>>>(W0, W1, Wb, ws);
    colmean_h<<<NROWS / 64, 1024, 0, stream>>>(x, Wb, b0, b1, ws);
    y2z_kernel<<<(NS * DIN * 64) / 256, 256, 0, stream>>>(W2, b2, eps, ws);
    pv_final_kernel<<<256, 256, 0, stream>>>(x, ws, eps, out, 256);
}